// Round 1
// baseline (725.154 us; speedup 1.0000x reference)
//
#include <hip/hip_runtime.h>
#include <math.h>

// ---------------- problem constants ----------------
#define NB 32
#define QL 32
#define DL 1024
#define EMB 300
#define OD 128
#define KNUM 21

// workspace layout (in floats)
static const int WT1_OFF = 0;                       // 300*128
static const int WT2_OFF = 38400;                   // 600*128
static const int WT3_OFF = 115200;                  // 900*128
static const int QENC_OFF = 230400;
static const int QENC_SZ = NB * QL * OD;            // 131072
static const int DENC_OFF = QENC_OFF + 3 * QENC_SZ; // 623616
static const int DENC_SZ = NB * DL * OD;            // 4194304
static const int ACC_OFF = DENC_OFF + 3 * DENC_SZ;  // 13206528
static const int ACC_SZ = 9 * NB * QL * KNUM;       // 193536

// ---------------- weight transpose: w[o][c][j] -> wT[(j*300+c)*128 + o] ----------------
__global__ void transpose_w_kernel(const float* __restrict__ w1,
                                   const float* __restrict__ w2,
                                   const float* __restrict__ w3,
                                   float* __restrict__ wt) {
    int idx = blockIdx.x * 256 + threadIdx.x;
    if (idx >= 230400) return;
    const float* src;
    int k, rel, base;
    if (idx < 38400)        { k = 1; rel = idx;          src = w1; base = 0; }
    else if (idx < 115200)  { k = 2; rel = idx - 38400;  src = w2; base = 38400; }
    else                    { k = 3; rel = idx - 115200; src = w3; base = 115200; }
    int m = rel >> 7;       // (j*300+c)
    int o = rel & 127;
    int j = m / 300;
    int c = m - j * 300;
    wt[base + rel] = src[(o * 300 + c) * k + j];
}

// ---------------- fused gather + conv GEMM + bias + relu ----------------
// out[b,l,o] = relu(bias[o] + sum_{j<K, c<300} emb[ids[b,l+j], c] * w[o,c,j])
// GEMM: M = 64 l's per block, N = 128 o, K-dim = 300*K in chunks of 30.
template <int K>
__global__ __launch_bounds__(256) void conv_gemm(const float* __restrict__ emb,
                                                 const int* __restrict__ ids,
                                                 int L, int Lmax,
                                                 const float* __restrict__ wT,
                                                 const float* __restrict__ bias,
                                                 float* __restrict__ out) {
    const int KD = 300 * K;
    const int NCH = KD / 30;
    __shared__ float Xs[64 * 31];   // [ml][kk], stride 31 (pad)
    __shared__ float Ws[30 * 128];  // [kk][o]
    const int tid = threadIdx.x;
    const int b = blockIdx.y;
    const int l0 = blockIdx.x * 64;
    const int Lk = L - K + 1;

    const int og = tid & 15;   // 16 o-groups of 8
    const int lg = tid >> 4;   // 16 l-groups of 4
    const int o0 = og * 8;
    const int lt = lg * 4;

    float acc[4][8];
#pragma unroll
    for (int i = 0; i < 4; ++i)
#pragma unroll
        for (int j = 0; j < 8; ++j) acc[i][j] = 0.f;

    const int kk_s = tid & 31;
    const int mlb = tid >> 5;

    for (int ch = 0; ch < NCH; ++ch) {
        const int k0 = ch * 30;
        const int c0 = k0 % 300;
        const int jj = k0 / 300;
        // stage W chunk (contiguous copy, 30*128 floats)
        {
            const float4* wsrc = reinterpret_cast<const float4*>(wT + k0 * 128);
            float4* wdst = reinterpret_cast<float4*>(Ws);
#pragma unroll
            for (int i = tid; i < 960; i += 256) wdst[i] = wsrc[i];
        }
        // stage X chunk: Xs[ml][kk] = emb[ids[b, l0+ml+jj]][c0+kk]
        if (kk_s < 30) {
#pragma unroll
            for (int pass = 0; pass < 8; ++pass) {
                int ml = mlb + pass * 8;
                int row = l0 + ml + jj;
                if (row > L - 1) row = L - 1;
                int rid = ids[b * L + row];
                Xs[ml * 31 + kk_s] = emb[rid * 300 + c0 + kk_s];
            }
        }
        __syncthreads();
#pragma unroll 5
        for (int kk = 0; kk < 30; ++kk) {
            float4 wa = *reinterpret_cast<const float4*>(&Ws[kk * 128 + o0]);
            float4 wb = *reinterpret_cast<const float4*>(&Ws[kk * 128 + o0 + 4]);
            float w[8] = {wa.x, wa.y, wa.z, wa.w, wb.x, wb.y, wb.z, wb.w};
            float x[4];
#pragma unroll
            for (int i = 0; i < 4; ++i) x[i] = Xs[(lt + i) * 31 + kk];
#pragma unroll
            for (int i = 0; i < 4; ++i)
#pragma unroll
                for (int j = 0; j < 8; ++j) acc[i][j] += x[i] * w[j];
        }
        __syncthreads();
    }
    // epilogue
    float4 ba = *reinterpret_cast<const float4*>(&bias[o0]);
    float4 bb = *reinterpret_cast<const float4*>(&bias[o0 + 4]);
    float bs[8] = {ba.x, ba.y, ba.z, ba.w, bb.x, bb.y, bb.z, bb.w};
#pragma unroll
    for (int i = 0; i < 4; ++i) {
        int l = l0 + lt + i;
        if (l < Lk) {
            float r[8];
#pragma unroll
            for (int j = 0; j < 8; ++j) r[j] = fmaxf(acc[i][j] + bs[j], 0.f);
            float* op = out + (b * Lmax + l) * OD + o0;
            *reinterpret_cast<float4*>(op) = make_float4(r[0], r[1], r[2], r[3]);
            *reinterpret_cast<float4*>(op + 4) = make_float4(r[4], r[5], r[6], r[7]);
        }
    }
}

// ---------------- normalize rows (128-dim) + fold mask ----------------
__global__ void normalize_kernel(float* __restrict__ enc, const float* __restrict__ mask,
                                 int Lk, int Lmax, int mstride) {
    int b = blockIdx.y;
    int l = blockIdx.x * 4 + (threadIdx.x >> 6);
    int lane = threadIdx.x & 63;
    if (l >= Lk) return;
    float* row = enc + (b * Lmax + l) * OD;
    float v0 = row[lane];
    float v1 = row[lane + 64];
    float ss = v0 * v0 + v1 * v1;
#pragma unroll
    for (int m = 32; m; m >>= 1) ss += __shfl_xor(ss, m, 64);
    float sc = mask[b * mstride + l] / (sqrtf(ss) + 1e-13f);
    row[lane] = v0 * sc;
    row[lane + 64] = v1 * sc;
}

// ---------------- matcher: dot tile + gaussian histogram ----------------
// grid: (vtile=8, b=32, pair=9), block 256.
__global__ __launch_bounds__(256) void matcher_kernel(const float* __restrict__ qenc,
                                                      const float* __restrict__ denc,
                                                      float* __restrict__ accb) {
    __shared__ float lds[10752];       // 43 KB
    float* Qs = lds;                   // 64 x 36  (2304 floats)
    float* Vs = lds + 2304;            // 64 x 132 (8448 floats)
    float* Sm = lds;                   // 32 x 129 (4128 floats), aliased after dots

    const int tid = threadIdx.x;
    const int p = blockIdx.z;
    const int b = blockIdx.y;
    const int v0 = blockIdx.x * 128;
    const int qi = p / 3;
    const int di = p - qi * 3;
    const int Qk = 32 - qi;            // 32 - ksize + 1, ksize = qi+1
    const int Vk = 1024 - di;
    const float* qptr = qenc + qi * QENC_SZ + b * (QL * OD);
    const float* vptr = denc + di * DENC_SZ + b * (DL * OD);

    const int vg = tid & 31;
    const int qg = tid >> 5;
    const int vt = vg * 4;
    const int qt = qg * 4;
    float acc[4][4];
#pragma unroll
    for (int i = 0; i < 4; ++i)
#pragma unroll
        for (int j = 0; j < 4; ++j) acc[i][j] = 0.f;

    const int kks = tid & 63;
    const int rb = tid >> 6;

    for (int ch = 0; ch < 2; ++ch) {
        const int k0 = ch * 64;
#pragma unroll
        for (int pass = 0; pass < 8; ++pass) {
            int q = rb + pass * 4;
            Qs[kks * 36 + q] = qptr[q * OD + k0 + kks];
        }
#pragma unroll
        for (int pass = 0; pass < 32; ++pass) {
            int v = rb + pass * 4;
            Vs[kks * 132 + v] = vptr[(v0 + v) * OD + k0 + kks];
        }
        __syncthreads();
#pragma unroll 4
        for (int k = 0; k < 64; ++k) {
            float4 qv = *reinterpret_cast<const float4*>(&Qs[k * 36 + qt]);
            float4 vv = *reinterpret_cast<const float4*>(&Vs[k * 132 + vt]);
            float qa[4] = {qv.x, qv.y, qv.z, qv.w};
            float va[4] = {vv.x, vv.y, vv.z, vv.w};
#pragma unroll
            for (int i = 0; i < 4; ++i)
#pragma unroll
                for (int j = 0; j < 4; ++j) acc[i][j] += qa[i] * va[j];
        }
        __syncthreads();
    }
    // S tile to LDS (aliases Qs/Vs; all reads done)
#pragma unroll
    for (int i = 0; i < 4; ++i)
#pragma unroll
        for (int j = 0; j < 4; ++j) Sm[(qt + i) * 129 + vt + j] = acc[i][j];
    __syncthreads();

    const int vmax = min(128, Vk - v0);
    for (int idx = tid; idx < 32 * KNUM; idx += 256) {
        int q = idx & 31;
        int t = idx >> 5;
        if (q < Qk) {
            float mu = (t == 0) ? 1.0f : (0.95f - 0.1f * (float)(t - 1));
            float cn = (t == 0) ? 5.0e5f : 50.0f;  // 1/(2 sigma^2)
            const float* srow = &Sm[q * 129];
            float a = 0.f;
            for (int v = 0; v < vmax; ++v) {
                float d = srow[v] - mu;
                a += __expf(-cn * (d * d));
            }
            atomicAdd(&accb[((p * NB + b) * QL + q) * KNUM + t], a);
        }
    }
}

// ---------------- finalize: log-pool over v-sums, mask, sum over q, dense ----------------
__global__ void finalize_kernel(const float* __restrict__ accb,
                                const float* __restrict__ qmask,
                                const float* __restrict__ dw,
                                const float* __restrict__ db,
                                float* __restrict__ out) {
    __shared__ float prod[192];
    int b = blockIdx.x;
    int tid = threadIdx.x;
    if (tid < 189) {
        int pq = tid / 21;
        int t = tid - pq * 21;
        int qi = pq / 3;
        int Qk = 32 - qi;
        const float* ab = accb + ((pq * NB + b) * QL) * KNUM + t;
        float s = 0.f;
        for (int q = 0; q < Qk; ++q)
            s += logf(fmaxf(ab[q * KNUM], 1e-10f)) * qmask[b * QL + q];
        float lg = s * 0.01f;
        out[NB + b * 189 + tid] = lg;
        prod[tid] = lg * dw[tid];
    }
    __syncthreads();
    if (tid == 0) {
        float sc = db[0];
        for (int i = 0; i < 189; ++i) sc += prod[i];
        out[b] = sc;
    }
}

// ---------------- launcher ----------------
extern "C" void kernel_launch(void* const* d_in, const int* in_sizes, int n_in,
                              void* d_out, int out_size, void* d_ws, size_t ws_size,
                              hipStream_t stream) {
    const int* qids = (const int*)d_in[0];
    const float* qmask = (const float*)d_in[1];
    const int* dids = (const int*)d_in[2];
    const float* dmask = (const float*)d_in[3];
    const float* emb = (const float*)d_in[4];
    const float* w1 = (const float*)d_in[5];
    const float* b1 = (const float*)d_in[6];
    const float* w2 = (const float*)d_in[7];
    const float* b2 = (const float*)d_in[8];
    const float* w3 = (const float*)d_in[9];
    const float* b3 = (const float*)d_in[10];
    const float* dw = (const float*)d_in[11];
    const float* db = (const float*)d_in[12];
    float* out = (float*)d_out;
    float* ws = (float*)d_ws;

    float* wt = ws;
    float* qenc = ws + QENC_OFF;
    float* denc = ws + DENC_OFF;
    float* accb = ws + ACC_OFF;

    hipMemsetAsync(accb, 0, ACC_SZ * sizeof(float), stream);
    transpose_w_kernel<<<900, 256, 0, stream>>>(w1, w2, w3, wt);

    conv_gemm<1><<<dim3(1, NB), 256, 0, stream>>>(emb, qids, QL, QL, wt + WT1_OFF, b1, qenc + 0 * QENC_SZ);
    conv_gemm<2><<<dim3(1, NB), 256, 0, stream>>>(emb, qids, QL, QL, wt + WT2_OFF, b2, qenc + 1 * QENC_SZ);
    conv_gemm<3><<<dim3(1, NB), 256, 0, stream>>>(emb, qids, QL, QL, wt + WT3_OFF, b3, qenc + 2 * QENC_SZ);
    conv_gemm<1><<<dim3(16, NB), 256, 0, stream>>>(emb, dids, DL, DL, wt + WT1_OFF, b1, denc + 0 * DENC_SZ);
    conv_gemm<2><<<dim3(16, NB), 256, 0, stream>>>(emb, dids, DL, DL, wt + WT2_OFF, b2, denc + 1 * DENC_SZ);
    conv_gemm<3><<<dim3(16, NB), 256, 0, stream>>>(emb, dids, DL, DL, wt + WT3_OFF, b3, denc + 2 * DENC_SZ);

    normalize_kernel<<<dim3(8, NB), 256, 0, stream>>>(qenc + 0 * QENC_SZ, qmask, 32, QL, QL);
    normalize_kernel<<<dim3(8, NB), 256, 0, stream>>>(qenc + 1 * QENC_SZ, qmask, 31, QL, QL);
    normalize_kernel<<<dim3(8, NB), 256, 0, stream>>>(qenc + 2 * QENC_SZ, qmask, 30, QL, QL);
    normalize_kernel<<<dim3(256, NB), 256, 0, stream>>>(denc + 0 * DENC_SZ, dmask, 1024, DL, DL);
    normalize_kernel<<<dim3(256, NB), 256, 0, stream>>>(denc + 1 * DENC_SZ, dmask, 1023, DL, DL);
    normalize_kernel<<<dim3(256, NB), 256, 0, stream>>>(denc + 2 * DENC_SZ, dmask, 1022, DL, DL);

    matcher_kernel<<<dim3(8, NB, 9), 256, 0, stream>>>(qenc, denc, accb);
    finalize_kernel<<<NB, 256, 0, stream>>>(accb, qmask, dw, db, out);
}

// Round 2
// 322.545 us; speedup vs baseline: 2.2482x; 2.2482x over previous
//
#include <hip/hip_runtime.h>
#include <hip/hip_bf16.h>
#include <math.h>

// ---------------- problem constants ----------------
#define NB 32
#define QL 32
#define DL 1024
#define EMB 300
#define EMBP 320            // padded embed dim (zeros 300..319)
#define OD 128
#define KNUM 21
#define VOCAB 50000

typedef short short8 __attribute__((ext_vector_type(8)));
typedef float floatx4 __attribute__((ext_vector_type(4)));

// workspace layout (in float units)
static const size_t WP_OFF = 0;                        // packed bf16 weights: 245760 ushorts = 122880 f
static const size_t EMB16_OFF = 122880;                // bf16 emb [VOCAB][320]: 16e6 ushorts = 8e6 f
static const size_t QENC_OFF = 8122880;
static const size_t QENC_SZ = NB * QL * OD;            // 131072
static const size_t DENC_OFF = QENC_OFF + 3 * QENC_SZ; // 8516096
static const size_t DENC_SZ = (size_t)NB * DL * OD;    // 4194304
static const size_t ACC_OFF = DENC_OFF + 3 * DENC_SZ;  // 21099008
static const int ACC_SZ = 9 * NB * QL * KNUM;          // 193536

// per-k offsets (ushorts) into packed weight buffer wp: [o][j*320+c]
__device__ __constant__ int WPOFF_C[3] = {0, 40960, 122880};

// ---------------- emb fp32 -> bf16, pad 300 -> 320 ----------------
__global__ void prep_emb_kernel(const float* __restrict__ emb, ushort* __restrict__ emb16) {
    int idx = blockIdx.x * 256 + threadIdx.x;   // one thread = 8 outputs
    if (idx >= VOCAB * 40) return;
    int r = idx / 40;
    int c0 = (idx - r * 40) * 8;
    ushort v[8];
#pragma unroll
    for (int i = 0; i < 8; ++i) {
        int c = c0 + i;
        float f = (c < EMB) ? emb[r * EMB + c] : 0.f;
        __hip_bfloat16 h = __float2bfloat16(f);
        v[i] = *reinterpret_cast<ushort*>(&h);
    }
    *reinterpret_cast<uint4*>(emb16 + (size_t)r * EMBP + c0) = *reinterpret_cast<uint4*>(v);
}

// ---------------- weights -> bf16, layout [o][j*320+c], zero-padded ----------------
__global__ void prep_w_kernel(const float* __restrict__ w1,
                              const float* __restrict__ w2,
                              const float* __restrict__ w3,
                              ushort* __restrict__ wp) {
    int idx = blockIdx.x * 256 + threadIdx.x;
    if (idx >= 245760) return;
    const float* src;
    int k, rel, base;
    if (idx < 40960)        { k = 1; rel = idx;          src = w1; base = 0; }
    else if (idx < 122880)  { k = 2; rel = idx - 40960;  src = w2; base = 40960; }
    else                    { k = 3; rel = idx - 122880; src = w3; base = 122880; }
    int kd = 320 * k;
    int o = rel / kd;
    int jc = rel - o * kd;
    int j = jc / EMBP;
    int c = jc - j * EMBP;
    float f = (c < EMB) ? src[(o * EMB + c) * k + j] : 0.f;
    __hip_bfloat16 h = __float2bfloat16(f);
    wp[base + rel] = *reinterpret_cast<ushort*>(&h);
}

// ---------------- fused gather + conv via bf16 MFMA ----------------
// grid: (mtiles, NB, 3). Block 256 = 4 waves, tile M=128 (l) x N=128 (o).
// K-dim = 320*(z+1), chunks of 64.
__global__ __launch_bounds__(256) void conv_mfma(const ushort* __restrict__ emb16,
                                                 const int* __restrict__ ids,
                                                 int L, int Lmax, size_t enc_sz,
                                                 const ushort* __restrict__ wp,
                                                 const float* __restrict__ b1,
                                                 const float* __restrict__ b2,
                                                 const float* __restrict__ b3,
                                                 float* __restrict__ enc) {
    __shared__ ushort As[128 * 72];   // [m][kk], stride 72 (pad 8)
    __shared__ ushort Bs[128 * 72];   // [o][kk], stride 72

    const int tid = threadIdx.x;
    const int b = blockIdx.y;
    const int z = blockIdx.z;         // ksize - 1
    const int Kdim = EMBP * (z + 1);
    const int NCH = Kdim >> 6;        // chunks of 64
    const int l0 = blockIdx.x * 128;
    const int Lk = L - z;
    const ushort* wpk = wp + WPOFF_C[z];
    const float* bias = (z == 0) ? b1 : ((z == 1) ? b2 : b3);
    float* out = enc + (size_t)z * enc_sz;

    const int wave = tid >> 6;
    const int lane = tid & 63;
    const int wm = wave >> 1;         // 0..1 : rows 64*wm..
    const int wn = wave & 1;          // 0..1 : cols 64*wn..
    const int l15 = lane & 15;
    const int quad = lane >> 4;

    // staging mapping: g = k-octet, mr = row base
    const int g = tid & 7;
    const int mr = tid >> 3;          // 0..31

    floatx4 acc[4][4];
#pragma unroll
    for (int i = 0; i < 4; ++i)
#pragma unroll
        for (int j = 0; j < 4; ++j) acc[i][j] = (floatx4)0.f;

    for (int ch = 0; ch < NCH; ++ch) {
        const int k0 = ch << 6;
        const int jj = k0 / EMBP;     // conv tap (chunk never straddles: 320/64=5)
        const int c0 = k0 - jj * EMBP;
#pragma unroll
        for (int p = 0; p < 4; ++p) {
            int m = mr + (p << 5);
            // A: gathered embedding row
            int l = l0 + m + jj;
            if (l > L - 1) l = L - 1;
            int rid = ids[b * L + l];
            uint4 av = *reinterpret_cast<const uint4*>(emb16 + (size_t)rid * EMBP + c0 + (g << 3));
            *reinterpret_cast<uint4*>(&As[m * 72 + (g << 3)]) = av;
            // B: weight row (o = m)
            uint4 bv = *reinterpret_cast<const uint4*>(wpk + (size_t)m * Kdim + k0 + (g << 3));
            *reinterpret_cast<uint4*>(&Bs[m * 72 + (g << 3)]) = bv;
        }
        __syncthreads();
#pragma unroll
        for (int h = 0; h < 2; ++h) {
            short8 af[4], bf[4];
#pragma unroll
            for (int i = 0; i < 4; ++i) {
                int m = wm * 64 + i * 16 + l15;
                af[i] = *reinterpret_cast<const short8*>(&As[m * 72 + h * 32 + (quad << 3)]);
                int n = wn * 64 + i * 16 + l15;
                bf[i] = *reinterpret_cast<const short8*>(&Bs[n * 72 + h * 32 + (quad << 3)]);
            }
#pragma unroll
            for (int i = 0; i < 4; ++i)
#pragma unroll
                for (int j = 0; j < 4; ++j)
                    acc[i][j] = __builtin_amdgcn_mfma_f32_16x16x32_bf16(af[i], bf[j], acc[i][j], 0, 0, 0);
        }
        __syncthreads();
    }

    // epilogue: bias + relu + store (C/D: col=lane&15 -> n, row=quad*4+reg -> m)
    float bv[4];
#pragma unroll
    for (int j = 0; j < 4; ++j) bv[j] = bias[wn * 64 + j * 16 + l15];
#pragma unroll
    for (int i = 0; i < 4; ++i) {
        int mbase = wm * 64 + i * 16 + quad * 4;
#pragma unroll
        for (int r = 0; r < 4; ++r) {
            int l = l0 + mbase + r;
            if (l < Lk) {
                float* op = out + ((size_t)(b * Lmax + l)) * OD + wn * 64 + l15;
#pragma unroll
                for (int j = 0; j < 4; ++j)
                    op[j * 16] = fmaxf(acc[i][j][r] + bv[j], 0.f);
            }
        }
    }
}

// ---------------- normalize rows (128-dim) + fold mask ----------------
__global__ void normalize_kernel(float* __restrict__ enc, const float* __restrict__ mask,
                                 int Lk, int Lmax, int mstride) {
    int b = blockIdx.y;
    int l = blockIdx.x * 4 + (threadIdx.x >> 6);
    int lane = threadIdx.x & 63;
    if (l >= Lk) return;
    float* row = enc + ((size_t)b * Lmax + l) * OD;
    float v0 = row[lane];
    float v1 = row[lane + 64];
    float ss = v0 * v0 + v1 * v1;
#pragma unroll
    for (int m = 32; m; m >>= 1) ss += __shfl_xor(ss, m, 64);
    float sc = mask[b * mstride + l] / (sqrtf(ss) + 1e-13f);
    row[lane] = v0 * sc;
    row[lane + 64] = v1 * sc;
}

// ---------------- matcher: dot tile + gaussian histogram ----------------
__global__ __launch_bounds__(256) void matcher_kernel(const float* __restrict__ qenc,
                                                      const float* __restrict__ denc,
                                                      float* __restrict__ accb) {
    __shared__ float lds[10752];       // 43 KB
    float* Qs = lds;                   // 64 x 36
    float* Vs = lds + 2304;            // 64 x 132
    float* Sm = lds;                   // 32 x 129, aliased after dots

    const int tid = threadIdx.x;
    const int p = blockIdx.z;
    const int b = blockIdx.y;
    const int v0 = blockIdx.x * 128;
    const int qi = p / 3;
    const int di = p - qi * 3;
    const int Qk = 32 - qi;
    const int Vk = 1024 - di;
    const float* qptr = qenc + qi * QENC_SZ + (size_t)b * (QL * OD);
    const float* vptr = denc + di * DENC_SZ + (size_t)b * (DL * OD);

    const int vg = tid & 31;
    const int qg = tid >> 5;
    const int vt = vg * 4;
    const int qt = qg * 4;
    float acc[4][4];
#pragma unroll
    for (int i = 0; i < 4; ++i)
#pragma unroll
        for (int j = 0; j < 4; ++j) acc[i][j] = 0.f;

    const int kks = tid & 63;
    const int rb = tid >> 6;

    for (int ch = 0; ch < 2; ++ch) {
        const int k0 = ch * 64;
#pragma unroll
        for (int pass = 0; pass < 8; ++pass) {
            int q = rb + pass * 4;
            Qs[kks * 36 + q] = qptr[q * OD + k0 + kks];
        }
#pragma unroll
        for (int pass = 0; pass < 32; ++pass) {
            int v = rb + pass * 4;
            Vs[kks * 132 + v] = vptr[(size_t)(v0 + v) * OD + k0 + kks];
        }
        __syncthreads();
#pragma unroll 4
        for (int k = 0; k < 64; ++k) {
            float4 qv = *reinterpret_cast<const float4*>(&Qs[k * 36 + qt]);
            float4 vv = *reinterpret_cast<const float4*>(&Vs[k * 132 + vt]);
            float qa[4] = {qv.x, qv.y, qv.z, qv.w};
            float va[4] = {vv.x, vv.y, vv.z, vv.w};
#pragma unroll
            for (int i = 0; i < 4; ++i)
#pragma unroll
                for (int j = 0; j < 4; ++j) acc[i][j] += qa[i] * va[j];
        }
        __syncthreads();
    }
#pragma unroll
    for (int i = 0; i < 4; ++i)
#pragma unroll
        for (int j = 0; j < 4; ++j) Sm[(qt + i) * 129 + vt + j] = acc[i][j];
    __syncthreads();

    const int vmax = min(128, Vk - v0);
    for (int idx = tid; idx < 32 * KNUM; idx += 256) {
        int q = idx & 31;
        int t = idx >> 5;
        if (q < Qk) {
            float mu = (t == 0) ? 1.0f : (0.95f - 0.1f * (float)(t - 1));
            float cn = (t == 0) ? 5.0e5f : 50.0f;
            const float* srow = &Sm[q * 129];
            float a = 0.f;
            for (int v = 0; v < vmax; ++v) {
                float d = srow[v] - mu;
                a += __expf(-cn * (d * d));
            }
            atomicAdd(&accb[((p * NB + b) * QL + q) * KNUM + t], a);
        }
    }
}

// ---------------- finalize ----------------
__global__ void finalize_kernel(const float* __restrict__ accb,
                                const float* __restrict__ qmask,
                                const float* __restrict__ dw,
                                const float* __restrict__ db,
                                float* __restrict__ out) {
    __shared__ float prod[192];
    int b = blockIdx.x;
    int tid = threadIdx.x;
    if (tid < 189) {
        int pq = tid / 21;
        int t = tid - pq * 21;
        int qi = pq / 3;
        int Qk = 32 - qi;
        const float* ab = accb + ((pq * NB + b) * QL) * KNUM + t;
        float s = 0.f;
        for (int q = 0; q < Qk; ++q)
            s += logf(fmaxf(ab[q * KNUM], 1e-10f)) * qmask[b * QL + q];
        float lg = s * 0.01f;
        out[NB + b * 189 + tid] = lg;
        prod[tid] = lg * dw[tid];
    }
    __syncthreads();
    if (tid == 0) {
        float sc = db[0];
        for (int i = 0; i < 189; ++i) sc += prod[i];
        out[b] = sc;
    }
}

// ---------------- launcher ----------------
extern "C" void kernel_launch(void* const* d_in, const int* in_sizes, int n_in,
                              void* d_out, int out_size, void* d_ws, size_t ws_size,
                              hipStream_t stream) {
    const int* qids = (const int*)d_in[0];
    const float* qmask = (const float*)d_in[1];
    const int* dids = (const int*)d_in[2];
    const float* dmask = (const float*)d_in[3];
    const float* emb = (const float*)d_in[4];
    const float* w1 = (const float*)d_in[5];
    const float* b1 = (const float*)d_in[6];
    const float* w2 = (const float*)d_in[7];
    const float* b2 = (const float*)d_in[8];
    const float* w3 = (const float*)d_in[9];
    const float* b3 = (const float*)d_in[10];
    const float* dw = (const float*)d_in[11];
    const float* db = (const float*)d_in[12];
    float* out = (float*)d_out;
    float* ws = (float*)d_ws;

    ushort* wp = (ushort*)(ws + WP_OFF);
    ushort* emb16 = (ushort*)(ws + EMB16_OFF);
    float* qenc = ws + QENC_OFF;
    float* denc = ws + DENC_OFF;
    float* accb = ws + ACC_OFF;

    hipMemsetAsync(accb, 0, ACC_SZ * sizeof(float), stream);
    prep_emb_kernel<<<(VOCAB * 40 + 255) / 256, 256, 0, stream>>>(emb, emb16);
    prep_w_kernel<<<960, 256, 0, stream>>>(w1, w2, w3, wp);

    // doc convs: all 3 ksizes in one launch
    conv_mfma<<<dim3(8, NB, 3), 256, 0, stream>>>(emb16, dids, DL, DL, DENC_SZ, wp, b1, b2, b3, denc);
    // query convs
    conv_mfma<<<dim3(1, NB, 3), 256, 0, stream>>>(emb16, qids, QL, QL, QENC_SZ, wp, b1, b2, b3, qenc);

    normalize_kernel<<<dim3(8, NB), 256, 0, stream>>>(qenc + 0 * QENC_SZ, qmask, 32, QL, QL);
    normalize_kernel<<<dim3(8, NB), 256, 0, stream>>>(qenc + 1 * QENC_SZ, qmask, 31, QL, QL);
    normalize_kernel<<<dim3(8, NB), 256, 0, stream>>>(qenc + 2 * QENC_SZ, qmask, 30, QL, QL);
    normalize_kernel<<<dim3(256, NB), 256, 0, stream>>>(denc + 0 * DENC_SZ, dmask, 1024, DL, DL);
    normalize_kernel<<<dim3(256, NB), 256, 0, stream>>>(denc + 1 * DENC_SZ, dmask, 1023, DL, DL);
    normalize_kernel<<<dim3(256, NB), 256, 0, stream>>>(denc + 2 * DENC_SZ, dmask, 1022, DL, DL);

    matcher_kernel<<<dim3(8, NB, 9), 256, 0, stream>>>(qenc, denc, accb);
    finalize_kernel<<<NB, 256, 0, stream>>>(accb, qmask, dw, db, out);
}